// Round 13
// baseline (229.840 us; speedup 1.0000x reference)
//
#include <hip/hip_runtime.h>

#define NTOT 65536      // 16*64*64 vectors
#define KC   8192       // codebook size
#define DV   64         // embedding dim
#define ZQN  4194304    // z_q elements
#define NSPL 4          // k-slices (r12 config: candidate set verified)
#define KSL  2048       // codes per slice
#define NTILE 16        // 128-code tiles per slice
#define CAP2 16         // candidate slots per n (clamp verified r14-r20)
#define SLA  44u        // append filter slack, 2^-20 units (~4.2e-5 > TH 3e-5)
#define SLE  40u        // E1 cross-slice filter slack (~3.8e-5 > TH 3e-5)

typedef unsigned int u32;
typedef unsigned long long u64;
typedef unsigned short ushort;
typedef short short8 __attribute__((ext_vector_type(8)));   // 8 bf16
typedef float float4v __attribute__((ext_vector_type(4)));  // MFMA acc

__device__ __forceinline__ short f2bf(float x) {           // fp32->bf16 RNE
    u32 u = __float_as_uint(x);
    u32 r = (u + 0x7fffu + ((u >> 16) & 1u)) >> 16;
    return (short)r;
}

// prep: fragment-order-shuffled bf16 codebook + ||e||^2 + zero cnt/lacc.
// (A[n] computed inside vq_e1 from its staged LDS z — prep reads no z.)
__global__ __launch_bounds__(256) void vq_prep(
    const float* __restrict__ emb, float* __restrict__ nrm,
    u32* __restrict__ cnt, double* __restrict__ lacc,
    ushort* __restrict__ ebs) {
    const int tid = blockIdx.x * 256 + threadIdx.x;    // 65536 threads
    const int t = tid >> 10, r = tid & 1023;
    const int s = r >> 7, r2 = r & 127, h = r2 >> 6, l = r2 & 63;
    const int q = l >> 4, c = l & 15;
    const float* src = emb + (size_t)((t * 128 + s * 16 + c) * 64 + h * 32 + q * 8);
    short8 v;
#pragma unroll
    for (int j = 0; j < 8; ++j) v[j] = f2bf(src[j]);
    *reinterpret_cast<short8*>(ebs + (size_t)tid * 8) = v;
    cnt[tid] = 0u;
    if (tid < KC) {
        double sacc = 0.0;
#pragma unroll
        for (int d = 0; d < DV; ++d) {
            double x = (double)emb[(size_t)tid * DV + d];
            sacc = fma(x, x, sacc);
        }
        nrm[tid] = (float)sacc;
    }
    if (tid == 0) *lacc = 0.0;
}

// MFMA screen pass — EXACT r12 structure (no LDS/no barriers; A-frags straight
// from L1/L2; ~85 µs verified 8x; issue-bound: VALU 58% + MFMA 34%).
// Candidate set bit-identical to r9/r11/r12/r18/r19/r20.
__global__ __launch_bounds__(256)
void vq_pass(const float* __restrict__ z, const ushort* __restrict__ ebs,
             u32* __restrict__ cnt, u32* __restrict__ cand) {
    const int tid = threadIdx.x;
    const int lane = tid & 63;
    const int nblk = blockIdx.x & 255, ks = blockIdx.x >> 8;
    const int nb = nblk * 256 + (tid >> 6) * 64;
    const int col = lane & 15, quad = lane >> 4;
    const int nlo = nb + col;

    // z B-frags in VGPRs (bitwise-identical conversion, rounds 5-9)
    short8 zf[4][2];
#pragma unroll
    for (int ns = 0; ns < 4; ++ns) {
        int n = nlo + ns * 16;
        const float* zp = z + (size_t)(n >> 12) * 262144 + (n & 4095);
#pragma unroll
        for (int t2 = 0; t2 < 2; ++t2)
#pragma unroll
            for (int j = 0; j < 8; ++j)
                zf[ns][t2][j] = f2bf(zp[(size_t)(t2 * 32 + quad * 8 + j) * 4096]);
    }

    u32 r0[4] = {0, 0, 0, 0}, r1[4] = {0, 0, 0, 0}, r2[4] = {0, 0, 0, 0};
    const char* gs = (const char*)ebs + (size_t)ks * (KSL * DV * 2);

    for (int t = 0; t < NTILE; ++t) {
#pragma unroll
        for (int g2 = 0; g2 < 4; ++g2) {            // 2 steps = 32 codes/group
            const char* tb = gs + t * 16384 + g2 * 4096;
            short8 a00 = *reinterpret_cast<const short8*>(tb + lane * 16);
            short8 a01 = *reinterpret_cast<const short8*>(tb + 1024 + lane * 16);
            short8 a10 = *reinterpret_cast<const short8*>(tb + 2048 + lane * 16);
            short8 a11 = *reinterpret_cast<const short8*>(tb + 3072 + lane * 16);
            // enc low: sign-offset | group6<<2 | quad2   (bits 8..15 zero)
            const u32 lowc = 0x80000000u + (u32)(((t * 4 + g2) << 2) | quad);
#pragma unroll
            for (int ns = 0; ns < 4; ++ns) {
                float4v acc0 = {0.f, 0.f, 0.f, 0.f};
                float4v acc1 = {0.f, 0.f, 0.f, 0.f};
                acc0 = __builtin_amdgcn_mfma_f32_16x16x32_bf16(a00, zf[ns][0], acc0, 0, 0, 0);
                acc0 = __builtin_amdgcn_mfma_f32_16x16x32_bf16(a01, zf[ns][1], acc0, 0, 0, 0);
                acc1 = __builtin_amdgcn_mfma_f32_16x16x32_bf16(a10, zf[ns][0], acc1, 0, 0, 0);
                acc1 = __builtin_amdgcn_mfma_f32_16x16x32_bf16(a11, zf[ns][1], acc1, 0, 0, 0);
                // max of 8 lane-local dots, v_max3-friendly shape
                float q0 = fmaxf(fmaxf(acc0[0], acc0[1]), acc0[2]);
                float q1 = fmaxf(fmaxf(acc0[3], acc1[0]), acc1[1]);
                float q2 = fmaxf(fmaxf(acc1[2], acc1[3]), q0);
                float m  = fmaxf(q2, q1);
                // |dot| < 0.0105 -> |int| < 11010 < 2^15: bias keeps monotone
                u32 e = ((u32)(int)(m * 1048576.0f) << 16) + lowc;
                u32 x  = min(r0[ns], e);            // top-3 network (5 ops)
                r0[ns] = max(r0[ns], e);
                u32 y  = min(r1[ns], x);
                r1[ns] = max(r1[ns], x);
                r2[ns] = max(r2[ns], y);
            }
        }
    }

    // slice-end: cross-quad max per n, filter top-3, append survivors
#pragma unroll
    for (int ns = 0; ns < 4; ++ns) {
        u32 m = r0[ns];
        m = max(m, __shfl_xor(m, 16));
        m = max(m, __shfl_xor(m, 32));
        const u32 thr = (m & 0xffff0000u) - (SLA << 16);
        const int n = nlo + ns * 16;
        const u32 tag = (u32)ks << 8;               // slice id, bits 8-9
        if (r0[ns] >= thr) {
            u32 p = atomicAdd(&cnt[n], 1u);
            if (p < CAP2) cand[(size_t)n * CAP2 + p] = r0[ns] | tag;
        }
        if (r1[ns] >= thr) {
            u32 p = atomicAdd(&cnt[n], 1u);
            if (p < CAP2) cand[(size_t)n * CAP2 + p] = r1[ns] | tag;
        }
        if (r2[ns] >= thr) {
            u32 p = atomicAdd(&cnt[n], 1u);
            if (p < CAP2) cand[(size_t)n * CAP2 + p] = r2[ns] | tag;
        }
    }
}

// E1 — r20 d-split structure (verified, bit-exact): 16 n/block, 16 thr/n;
// lane pairs split d (dh=0: d%4 in {0,1}; dh=1: {2,3}), 32 register-resident
// z floats each, partner halves summed via shfl_xor(1) in the exact u0..u3
// association order -> bitwise-identical d. In-kernel A[n] (serial f64 chain
// from staged LDS, one thread per n — bit-identical to prep's).
__global__ __launch_bounds__(256) void vq_e1(
    const float* __restrict__ z, const float* __restrict__ emb,
    const float* __restrict__ nrm, const u32* __restrict__ cnt,
    const u32* __restrict__ cand, int* __restrict__ idxw,
    float* __restrict__ out) {
    __shared__ float zs[64][20];                      // 16 n + pad, 5.1 KB
    __shared__ float As[16];
    const int tid = threadIdx.x;
    const int n0 = blockIdx.x * 16;                   // 16 n per block
    const int b = n0 >> 12, hw0 = n0 & 4095;          // same b for whole block
    // cooperative stage: 256 thr x 1 float4 = 1024 floats (16 n x 64 d)
    {
        const float* zb = z + (size_t)b * 262144 + hw0;
        const int d = tid >> 2, i4 = (tid & 3) * 4;
        float4 v = *reinterpret_cast<const float4*>(zb + (size_t)d * 4096 + i4);
        *reinterpret_cast<float4*>(&zs[d][i4]) = v;
    }
    __syncthreads();

    const int li  = tid >> 4;                         // local n 0..15
    const int n   = n0 + li;
    const int sub = tid & 15;                         // 16 threads per n
    const int dh  = sub & 1;                          // d-half of the pair
    const int j4  = (sub >> 1) & 3;                   // cand stride-4 offset
    const int st  = sub >> 3;                         // st-half

    // A[n] = ||z_n||^2: serial f64 chain from LDS (bit-identical to prep's)
    if (sub == 0) {
        double ad = 0.0;
#pragma unroll
        for (int d = 0; d < DV; ++d) {
            double x = (double)zs[d][li];
            ad = fma(x, x, ad);
        }
        As[li] = (float)ad;
    }

    u32 c = min(cnt[n], (u32)CAP2);                   // provably <= 12
    u32 emax = 0u;
    for (u32 j = 0; j < c; ++j) {
        u32 e = cand[(size_t)n * CAP2 + j];
        if (e > emax) emax = e;
    }
    const u32 ethr = (emax & 0xffff0000u) - (SLE << 16);

    // 32 register-resident z values for this half: d = 16*i2+4*k+2*dh+{0,1}
    float zh[32];
#pragma unroll
    for (int i = 0; i < 16; ++i) {
        zh[2 * i]     = zs[4 * i + 2 * dh][li];
        zh[2 * i + 1] = zs[4 * i + 2 * dh + 1][li];
    }

    // compact surviving candidates (max 3 per thread: j4, j4+4, j4+8)
    u32 surv[3]; int nsv = 0;
    for (u32 j = (u32)j4; j < c; j += 4) {
        u32 e = cand[(size_t)n * CAP2 + j];
        if (e >= ethr) surv[nsv++] = e;
    }

    __syncthreads();                                  // As ready
    const float A = As[li];

    float dmin = 1e30f;
    int kmin = 0x7fffffff;
    for (int i = 0; i < nsv; ++i) {
        u32 e = surv[i];
        int s   = (int)(e >> 8) & 3;
        int grp = (int)(e >> 2) & 63;
        int q   = (int)e & 3;
        int base = s * KSL + grp * 32 + q * 4 + st * 16;
#pragma unroll
        for (int r = 0; r < 4; ++r) {
            const int k = base + r;
            const float* ep = emb + (size_t)k * DV + 2 * dh;
            float dd;
            {
#pragma clang fp contract(off)
                float a0 = 0.f, a1 = 0.f;
#pragma unroll
                for (int i2 = 0; i2 < 4; ++i2) {
                    float2 v0 = *reinterpret_cast<const float2*>(ep + 16 * i2 + 0);
                    float2 v1 = *reinterpret_cast<const float2*>(ep + 16 * i2 + 4);
                    float2 v2 = *reinterpret_cast<const float2*>(ep + 16 * i2 + 8);
                    float2 v3 = *reinterpret_cast<const float2*>(ep + 16 * i2 + 12);
                    a0 = (zh[(i2*4+0)*2] * v0.x) + ((zh[(i2*4+1)*2] * v1.x) +
                         ((zh[(i2*4+2)*2] * v2.x) + ((zh[(i2*4+3)*2] * v3.x) + a0)));
                    a1 = (zh[(i2*4+0)*2+1] * v0.y) + ((zh[(i2*4+1)*2+1] * v1.y) +
                         ((zh[(i2*4+2)*2+1] * v2.y) + ((zh[(i2*4+3)*2+1] * v3.y) + a1)));
                }
                float sh = a0 + a1;                   // s01 (dh=0) or s23 (dh=1)
                float ot = __shfl_xor(sh, 1, 64);     // partner's half
                float dot = sh + ot;                  // IEEE add: same both lanes
                dd  = (A + nrm[k]) - (2.0f * dot);
            }
            if (dd < dmin || (dd == dmin && k < kmin)) { dmin = dd; kmin = k; }
        }
    }
    u64 key = ((u64)__float_as_uint(dmin) << 32) | (u32)kmin;   // d > 0
    u64 o1 = __shfl_xor(key, 1, 64); if (o1 < key) key = o1;
    u64 o2 = __shfl_xor(key, 2, 64); if (o2 < key) key = o2;
    u64 o4 = __shfl_xor(key, 4, 64); if (o4 < key) key = o4;
    u64 o8 = __shfl_xor(key, 8, 64); if (o8 < key) key = o8;
    if (sub == 0) {
        int km = (int)(key & 0xffffffffu);
        idxw[n] = km;
        out[(size_t)ZQN + 1 + n] = (float)km;
    }
}

// E2 (r21): z_q gather-store + loss, regrid 1024x(64n) -> 2048x(32n):
// 8 threads/n x 8 channels halves the per-thread load/store chain and
// doubles resident waves (16 -> 32 waves/CU, HW max) — E2 was latency-bound
// at ~22 µs vs its ~5.5 µs BW floor. Lanes 0-31 = consecutive n -> 128 B
// coalesced runs (2 segments/instruction). Loss math identical per element;
// only f64 reduction association changes (~1e-15, invisible).
__global__ __launch_bounds__(256) void vq_e2(
    const float* __restrict__ z, const float* __restrict__ emb,
    const int* __restrict__ idxw, float* __restrict__ out,
    double* __restrict__ lacc) {
    __shared__ double red[4];
    const int tid = threadIdx.x;
    const int n = blockIdx.x * 32 + (tid & 31);
    const int part = tid >> 5;                        // 8 channels per part
    const int b = n >> 12, hw = n & 4095;
    const int kmin = idxw[n];
    const float* zp = z + (size_t)b * 262144 + hw;
    const float4* er4 = (const float4*)(emb + (size_t)kmin * DV + part * 8);
    double lsum = 0.0;
#pragma unroll
    for (int i4 = 0; i4 < 2; ++i4) {
        float4 ev = er4[i4];
#pragma unroll
        for (int u = 0; u < 4; ++u) {
            int c = part * 8 + i4 * 4 + u;
            float v = (u == 0) ? ev.x : (u == 1) ? ev.y : (u == 2) ? ev.z : ev.w;
            out[(size_t)b * 262144 + (size_t)c * 4096 + hw] = v;
            double dv = (double)v - (double)zp[(size_t)c * 4096];
            lsum = fma(dv, dv, lsum);
        }
    }
#pragma unroll
    for (int off = 32; off > 0; off >>= 1)
        lsum += __shfl_down(lsum, off, 64);
    if ((tid & 63) == 0) red[tid >> 6] = lsum;
    __syncthreads();
    if (tid == 0)
        atomicAdd(lacc, red[0] + red[1] + red[2] + red[3]);
}

__global__ void vq_fin(const double* __restrict__ lacc, float* __restrict__ out) {
    if (threadIdx.x == 0)
        out[ZQN] = (float)(1.25 * (*lacc) / (double)ZQN);
}

extern "C" void kernel_launch(void* const* d_in, const int* in_sizes, int n_in,
                              void* d_out, int out_size, void* d_ws, size_t ws_size,
                              hipStream_t stream) {
    const float* z   = (const float*)d_in[0];
    const float* emb = (const float*)d_in[1];
    float* out = (float*)d_out;

    // d_out scratch inside the z_q span (16.77 MB), consumed before E2 stores:
    ushort* ebs  = (ushort*)d_out;                       // 1 MiB shuffled bf16
    u32*    cand = (u32*)((char*)d_out + 1048576);       // 4 MiB (ends 5 MiB)
    // ws scratch (~550 KB, under the proven 2.13 MB):
    double* lacc   = (double*)d_ws;                      // 8 B
    float*  nrm    = (float*)((char*)d_ws + 64);         // 32 KB
    u32*    cnt    = (u32*)((char*)d_ws + 32832);        // 256 KB
    int*    idxw   = (int*)((char*)d_ws + 294976);       // 256 KB

    vq_prep<<<256, 256, 0, stream>>>(emb, nrm, cnt, lacc, ebs);
    vq_pass<<<NSPL * 256, 256, 0, stream>>>(z, ebs, cnt, cand);
    vq_e1<<<4096, 256, 0, stream>>>(z, emb, nrm, cnt, cand, idxw, out);
    vq_e2<<<2048, 256, 0, stream>>>(z, emb, idxw, out, lacc);
    vq_fin<<<1, 64, 0, stream>>>(lacc, out);
}

// Round 16
// 209.750 us; speedup vs baseline: 1.0958x; 1.0958x over previous
//
#include <hip/hip_runtime.h>

#define NTOT 65536      // 16*64*64 vectors
#define KC   8192       // codebook size
#define DV   64         // embedding dim
#define ZQN  4194304    // z_q elements
#define NSPL 4          // k-slices
#define KSL  2048       // codes per slice
#define CAP2 16         // candidate slots per n (appends <= 6/slice/n now)
#define SLA  44u        // append filter slack, 2^-20 units (~4.2e-5 > TH 3e-5)
#define SLE  40u        // E1 cross-slice filter slack (~3.8e-5 > TH 3e-5)

typedef unsigned int u32;
typedef unsigned long long u64;
typedef unsigned short ushort;
typedef short short8 __attribute__((ext_vector_type(8)));    // 8 bf16
typedef float float16v __attribute__((ext_vector_type(16))); // 32x32 MFMA acc

__device__ __forceinline__ short f2bf(float x) {           // fp32->bf16 RNE
    u32 u = __float_as_uint(x);
    u32 r = (u + 0x7fffu + ((u >> 16) & 1u)) >> 16;
    return (short)r;
}

// prep (r23): codebook shuffled for 32x32x16 A-frags. Layout: byte address
// cg*4096 + kc*1024 + l*16 holds codebook[cg*32 + (l&31)][kc*16 + (l>>5)*8
// .. +8) as bf16 — lane l of a wave reading tb+l*16 gets its A operand
// (row=lane&31, k=(lane>>5)*8+j, the 16x16x32 family pattern scaled).
// Also ||e||^2 + zero cnt/lacc. (A[n] computed inside vq_e1.)
__global__ __launch_bounds__(256) void vq_prep(
    const float* __restrict__ emb, float* __restrict__ nrm,
    u32* __restrict__ cnt, double* __restrict__ lacc,
    ushort* __restrict__ ebs) {
    const int tid = blockIdx.x * 256 + threadIdx.x;    // 65536 threads
    const int l = tid & 63, kc = (tid >> 6) & 3, cg = tid >> 8;
    const int code = cg * 32 + (l & 31);
    const int d = kc * 16 + (l >> 5) * 8;
    const float* src = emb + (size_t)code * 64 + d;
    short8 v;
#pragma unroll
    for (int j = 0; j < 8; ++j) v[j] = f2bf(src[j]);
    *reinterpret_cast<short8*>(ebs + (size_t)tid * 8) = v;
    cnt[tid] = 0u;
    if (tid < KC) {
        double sacc = 0.0;
#pragma unroll
        for (int dd = 0; dd < DV; ++dd) {
            double x = (double)emb[(size_t)tid * DV + dd];
            sacc = fma(x, x, sacc);
        }
        nrm[tid] = (float)sacc;
    }
    if (tid == 0) *lacc = 0.0;
}

// MFMA screen pass (r23): 32x32x16 bf16 — one 4-MFMA chain = 32 codes x 32 n
// over K=64. Halves MFMA count (512/wave/slice) and cuts screen VALU ~20%
// (each lane owns 16 dots = 2 cells of 8). No LDS/no barriers (r12 insight).
// C/D rows: (reg&3)+8*(reg>>2)+4*hi -> cell(cb,hi) = g*32+cb*16+hi*4+{0..3,
// 8..11}. enc low byte: g<<2 | cb<<1 | hi; bits 8-15 zero for slice tag.
// Filter semantics: per-cell max vs (per-n-slice max - SLA) — partition-
// independent correctness (argmin's cell max within TH<slack of max).
__global__ __launch_bounds__(256) __attribute__((amdgpu_waves_per_eu(4, 4)))
void vq_pass(const float* __restrict__ z, const ushort* __restrict__ ebs,
             u32* __restrict__ cnt, u32* __restrict__ cand) {
    const int tid = threadIdx.x;
    const int lane = tid & 63;
    const int nblk = blockIdx.x & 255, ks = blockIdx.x >> 8;
    const int nb = nblk * 256 + (tid >> 6) * 64;       // 64 n per wave
    const int col = lane & 31, hi = lane >> 5, hi8 = hi * 8;

    // z B-frags: B[k][n], col=lane&31, k=(lane>>5)*8+j per 16-k chunk
    short8 zf[2][4];
#pragma unroll
    for (int nsub = 0; nsub < 2; ++nsub) {
        int n = nb + nsub * 32 + col;
        const float* zp = z + (size_t)(n >> 12) * 262144 + (n & 4095);
#pragma unroll
        for (int kc = 0; kc < 4; ++kc)
#pragma unroll
            for (int j = 0; j < 8; ++j)
                zf[nsub][kc][j] = f2bf(zp[(size_t)(kc * 16 + hi8 + j) * 4096]);
    }

    u32 r0[2] = {0, 0}, r1[2] = {0, 0}, r2[2] = {0, 0};
    const char* gs = (const char*)ebs + (size_t)ks * (KSL * DV * 2);

    for (int t = 0; t < 16; ++t) {
#pragma unroll
        for (int g2 = 0; g2 < 4; ++g2) {               // group g = 32 codes
            const int g = t * 4 + g2;
            const char* tb = gs + g * 4096;
            short8 a0 = *reinterpret_cast<const short8*>(tb + lane * 16);
            short8 a1 = *reinterpret_cast<const short8*>(tb + 1024 + lane * 16);
            short8 a2 = *reinterpret_cast<const short8*>(tb + 2048 + lane * 16);
            short8 a3 = *reinterpret_cast<const short8*>(tb + 3072 + lane * 16);
            const u32 lowc0 = 0x80000000u + (u32)((g << 2) | hi);   // cb=0
            const u32 lowc1 = lowc0 + 2u;                           // cb=1
#pragma unroll
            for (int nsub = 0; nsub < 2; ++nsub) {
                float16v acc = {0.f,0.f,0.f,0.f,0.f,0.f,0.f,0.f,
                                0.f,0.f,0.f,0.f,0.f,0.f,0.f,0.f};
                acc = __builtin_amdgcn_mfma_f32_32x32x16_bf16(a0, zf[nsub][0], acc, 0, 0, 0);
                acc = __builtin_amdgcn_mfma_f32_32x32x16_bf16(a1, zf[nsub][1], acc, 0, 0, 0);
                acc = __builtin_amdgcn_mfma_f32_32x32x16_bf16(a2, zf[nsub][2], acc, 0, 0, 0);
                acc = __builtin_amdgcn_mfma_f32_32x32x16_bf16(a3, zf[nsub][3], acc, 0, 0, 0);
                // cell 0: regs 0..7 (codes g*32+hi*4+{0..3,8..11})
                {
                    float q0 = fmaxf(fmaxf(acc[0], acc[1]), acc[2]);
                    float q1 = fmaxf(fmaxf(acc[3], acc[4]), acc[5]);
                    float q2 = fmaxf(fmaxf(acc[6], acc[7]), q0);
                    float m  = fmaxf(q2, q1);
                    u32 e = ((u32)(int)(m * 1048576.0f) << 16) + lowc0;
                    u32 x  = min(r0[nsub], e);
                    r0[nsub] = max(r0[nsub], e);
                    u32 y  = min(r1[nsub], x);
                    r1[nsub] = max(r1[nsub], x);
                    r2[nsub] = max(r2[nsub], y);
                }
                // cell 1: regs 8..15 (codes g*32+16+hi*4+{0..3,8..11})
                {
                    float q0 = fmaxf(fmaxf(acc[8], acc[9]), acc[10]);
                    float q1 = fmaxf(fmaxf(acc[11], acc[12]), acc[13]);
                    float q2 = fmaxf(fmaxf(acc[14], acc[15]), q0);
                    float m  = fmaxf(q2, q1);
                    u32 e = ((u32)(int)(m * 1048576.0f) << 16) + lowc1;
                    u32 x  = min(r0[nsub], e);
                    r0[nsub] = max(r0[nsub], e);
                    u32 y  = min(r1[nsub], x);
                    r1[nsub] = max(r1[nsub], x);
                    r2[nsub] = max(r2[nsub], y);
                }
            }
        }
    }

    // slice-end: cross-half max per n (lanes l and l+32 share n), filter,
    // append survivors (<= 2 halves x 3 per n per slice)
#pragma unroll
    for (int nsub = 0; nsub < 2; ++nsub) {
        u32 m = max(r0[nsub], (u32)__shfl_xor(r0[nsub], 32, 64));
        const u32 thr = (m & 0xffff0000u) - (SLA << 16);
        const int n = nb + nsub * 32 + col;
        const u32 tag = (u32)ks << 8;                  // slice id, bits 8-9
        if (r0[nsub] >= thr) {
            u32 p = atomicAdd(&cnt[n], 1u);
            if (p < CAP2) cand[(size_t)n * CAP2 + p] = r0[nsub] | tag;
        }
        if (r1[nsub] >= thr) {
            u32 p = atomicAdd(&cnt[n], 1u);
            if (p < CAP2) cand[(size_t)n * CAP2 + p] = r1[nsub] | tag;
        }
        if (r2[nsub] >= thr) {
            u32 p = atomicAdd(&cnt[n], 1u);
            if (p < CAP2) cand[(size_t)n * CAP2 + p] = r2[nsub] | tag;
        }
    }
}

// E1 — r20 d-split structure (verified bit-exact), decode updated for the
// 32x32 cell map: cand cell -> 8 codes = base + st*8 + r, base = s*KSL +
// grp*32 + cb*16 + hi*4. 16 n/block, 16 thr/n (dh d-pair, j4 cand-stride,
// st run-select); 32 register-resident z floats; partner halves summed via
// shfl_xor(1) in the exact u0..u3 association order -> bitwise-identical d.
// In-kernel A[n] (serial f64 chain from staged LDS, bit-identical).
__global__ __launch_bounds__(256) void vq_e1(
    const float* __restrict__ z, const float* __restrict__ emb,
    const float* __restrict__ nrm, const u32* __restrict__ cnt,
    const u32* __restrict__ cand, int* __restrict__ idxw,
    float* __restrict__ out) {
    __shared__ float zs[64][20];                      // 16 n + pad, 5.1 KB
    __shared__ float As[16];
    const int tid = threadIdx.x;
    const int n0 = blockIdx.x * 16;                   // 16 n per block
    const int b = n0 >> 12, hw0 = n0 & 4095;          // same b for whole block
    // cooperative stage: 256 thr x 1 float4 = 1024 floats (16 n x 64 d)
    {
        const float* zb = z + (size_t)b * 262144 + hw0;
        const int d = tid >> 2, i4 = (tid & 3) * 4;
        float4 v = *reinterpret_cast<const float4*>(zb + (size_t)d * 4096 + i4);
        *reinterpret_cast<float4*>(&zs[d][i4]) = v;
    }
    __syncthreads();

    const int li  = tid >> 4;                         // local n 0..15
    const int n   = n0 + li;
    const int sub = tid & 15;                         // 16 threads per n
    const int dh  = sub & 1;                          // d-half of the pair
    const int j4  = (sub >> 1) & 3;                   // cand stride-4 offset
    const int st  = sub >> 3;                         // code-run select

    // A[n] = ||z_n||^2: serial f64 chain from LDS (bit-identical to ref's)
    if (sub == 0) {
        double ad = 0.0;
#pragma unroll
        for (int d = 0; d < DV; ++d) {
            double x = (double)zs[d][li];
            ad = fma(x, x, ad);
        }
        As[li] = (float)ad;
    }

    u32 c = min(cnt[n], (u32)CAP2);
    u32 emax = 0u;
    for (u32 j = 0; j < c; ++j) {
        u32 e = cand[(size_t)n * CAP2 + j];
        if (e > emax) emax = e;
    }
    const u32 ethr = (emax & 0xffff0000u) - (SLE << 16);

    // 32 register-resident z values for this half: d = 16*i2+4*k+2*dh+{0,1}
    float zh[32];
#pragma unroll
    for (int i = 0; i < 16; ++i) {
        zh[2 * i]     = zs[4 * i + 2 * dh][li];
        zh[2 * i + 1] = zs[4 * i + 2 * dh + 1][li];
    }

    // compact surviving candidates (max 3 per thread: j4, j4+4, j4+8)
    u32 surv[3]; int nsv = 0;
    for (u32 j = (u32)j4; j < c; j += 4) {
        u32 e = cand[(size_t)n * CAP2 + j];
        if (e >= ethr) surv[nsv++] = e;
    }

    __syncthreads();                                  // As ready
    const float A = As[li];

    float dmin = 1e30f;
    int kmin = 0x7fffffff;
    for (int i = 0; i < nsv; ++i) {
        u32 e = surv[i];
        int s   = (int)(e >> 8) & 3;
        int grp = (int)(e >> 2) & 63;
        int cb  = (int)(e >> 1) & 1;
        int hi  = (int)e & 1;
        int base = s * KSL + grp * 32 + cb * 16 + hi * 4 + st * 8;
#pragma unroll
        for (int r = 0; r < 4; ++r) {
            const int k = base + r;
            const float* ep = emb + (size_t)k * DV + 2 * dh;
            float dd;
            {
#pragma clang fp contract(off)
                float a0 = 0.f, a1 = 0.f;
#pragma unroll
                for (int i2 = 0; i2 < 4; ++i2) {
                    float2 v0 = *reinterpret_cast<const float2*>(ep + 16 * i2 + 0);
                    float2 v1 = *reinterpret_cast<const float2*>(ep + 16 * i2 + 4);
                    float2 v2 = *reinterpret_cast<const float2*>(ep + 16 * i2 + 8);
                    float2 v3 = *reinterpret_cast<const float2*>(ep + 16 * i2 + 12);
                    a0 = (zh[(i2*4+0)*2] * v0.x) + ((zh[(i2*4+1)*2] * v1.x) +
                         ((zh[(i2*4+2)*2] * v2.x) + ((zh[(i2*4+3)*2] * v3.x) + a0)));
                    a1 = (zh[(i2*4+0)*2+1] * v0.y) + ((zh[(i2*4+1)*2+1] * v1.y) +
                         ((zh[(i2*4+2)*2+1] * v2.y) + ((zh[(i2*4+3)*2+1] * v3.y) + a1)));
                }
                float sh = a0 + a1;                   // s01 (dh=0) or s23 (dh=1)
                float ot = __shfl_xor(sh, 1, 64);     // partner's half
                float dot = sh + ot;                  // IEEE add: same both lanes
                dd  = (A + nrm[k]) - (2.0f * dot);
            }
            if (dd < dmin || (dd == dmin && k < kmin)) { dmin = dd; kmin = k; }
        }
    }
    u64 key = ((u64)__float_as_uint(dmin) << 32) | (u32)kmin;   // d > 0
    u64 o1 = __shfl_xor(key, 1, 64); if (o1 < key) key = o1;
    u64 o2 = __shfl_xor(key, 2, 64); if (o2 < key) key = o2;
    u64 o4 = __shfl_xor(key, 4, 64); if (o4 < key) key = o4;
    u64 o8 = __shfl_xor(key, 8, 64); if (o8 < key) key = o8;
    if (sub == 0) {
        int km = (int)(key & 0xffffffffu);
        idxw[n] = km;
        out[(size_t)ZQN + 1 + n] = (float)km;
    }
}

// E2: z_q gather-store + loss — EXACT r12/r18/r19/r20 structure (64 n/block,
// 4 waves split 64 channels, 256 B fully-coalesced runs).
__global__ __launch_bounds__(256) void vq_e2(
    const float* __restrict__ z, const float* __restrict__ emb,
    const int* __restrict__ idxw, float* __restrict__ out,
    double* __restrict__ lacc) {
    __shared__ double red[4];
    const int tid = threadIdx.x;
    const int n = blockIdx.x * 64 + (tid & 63);
    const int part = tid >> 6;                        // 16 channels per wave
    const int b = n >> 12, hw = n & 4095;
    const int kmin = idxw[n];
    const float* zp = z + (size_t)b * 262144 + hw;
    const float4* er4 = (const float4*)(emb + (size_t)kmin * DV + part * 16);
    double lsum = 0.0;
#pragma unroll
    for (int i4 = 0; i4 < 4; ++i4) {
        float4 ev = er4[i4];
#pragma unroll
        for (int u = 0; u < 4; ++u) {
            int c = part * 16 + i4 * 4 + u;
            float v = (u == 0) ? ev.x : (u == 1) ? ev.y : (u == 2) ? ev.z : ev.w;
            out[(size_t)b * 262144 + (size_t)c * 4096 + hw] = v;
            double dv = (double)v - (double)zp[(size_t)c * 4096];
            lsum = fma(dv, dv, lsum);
        }
    }
#pragma unroll
    for (int off = 32; off > 0; off >>= 1)
        lsum += __shfl_down(lsum, off, 64);
    if ((tid & 63) == 0) red[tid >> 6] = lsum;
    __syncthreads();
    if (tid == 0)
        atomicAdd(lacc, red[0] + red[1] + red[2] + red[3]);
}

__global__ void vq_fin(const double* __restrict__ lacc, float* __restrict__ out) {
    if (threadIdx.x == 0)
        out[ZQN] = (float)(1.25 * (*lacc) / (double)ZQN);
}

extern "C" void kernel_launch(void* const* d_in, const int* in_sizes, int n_in,
                              void* d_out, int out_size, void* d_ws, size_t ws_size,
                              hipStream_t stream) {
    const float* z   = (const float*)d_in[0];
    const float* emb = (const float*)d_in[1];
    float* out = (float*)d_out;

    // d_out scratch inside the z_q span (16.77 MB), consumed before E2 stores:
    ushort* ebs  = (ushort*)d_out;                       // 1 MiB shuffled bf16
    u32*    cand = (u32*)((char*)d_out + 1048576);       // 4 MiB (ends 5 MiB)
    // ws scratch (~550 KB, under the proven 2.13 MB):
    double* lacc   = (double*)d_ws;                      // 8 B
    float*  nrm    = (float*)((char*)d_ws + 64);         // 32 KB
    u32*    cnt    = (u32*)((char*)d_ws + 32832);        // 256 KB
    int*    idxw   = (int*)((char*)d_ws + 294976);       // 256 KB

    vq_prep<<<256, 256, 0, stream>>>(emb, nrm, cnt, lacc, ebs);
    vq_pass<<<NSPL * 256, 256, 0, stream>>>(z, ebs, cnt, cand);
    vq_e1<<<4096, 256, 0, stream>>>(z, emb, nrm, cnt, cand, idxw, out);
    vq_e2<<<1024, 256, 0, stream>>>(z, emb, idxw, out, lacc);
    vq_fin<<<1, 64, 0, stream>>>(lacc, out);
}